// Round 13
// baseline (482.211 us; speedup 1.0000x reference)
//
#include <hip/hip_runtime.h>
#include <stdint.h>

#define V_ITEMS 100000
#define EDIM    128
#define BATCH   4096
#define HLEN    50
#define TOPK    21

#define MT      64                      // batches per block in K2
#define MS      4                       // 16-row MFMA sub-blocks (MT/16)
#define VSPLIT  4                       // item-range splits (R4-proven overhead level)
#define NWAVE   12                      // waves per block (768 thr) -> 3 waves/SIMD
#define NCHUNK_TOT (V_ITEMS / 16)       // 6250 16-item chunks total
#define NITER   132                     // ceil(1563/12)=131 -> 132 (even)
#define CAP2    256                     // per-batch candidate capacity (R4-proven)
#define NKEEP   32                      // superset kept per (batch, range)
#define NCAND   (NKEEP * VSPLIT)        // 128 candidates per batch into K3
#define CONVB   ((V_ITEMS * EDIM) / (256 * 8))   // 6250 conv blocks in prep

typedef __attribute__((ext_vector_type(8))) short          bf16x8;
typedef __attribute__((ext_vector_type(4))) float          f32x4;
typedef __attribute__((ext_vector_type(8))) unsigned short u16x8;

__device__ inline unsigned short f2bf(float x) {           // RNE fp32->bf16
    unsigned u = __float_as_uint(x);
    return (unsigned short)((u + 0x7FFFu + ((u >> 16) & 1u)) >> 16);
}

// ------- prep: fused {emb fp32->bf16 table} + {mean-pool queries} -----------
// Block-class dispatch: blocks [0,CONVB) convert the table (8 floats/thread);
// blocks [CONVB, CONVB+2048) each pool 2 batches (128 threads per batch).
// Fusing overlaps the BW-bound convert with the latency-bound gather and
// removes one launch gap.
__global__ __launch_bounds__(256) void prep(
        const float* __restrict__ emb, unsigned short* __restrict__ ebf,
        const int* __restrict__ seq, const int* __restrict__ len,
        unsigned short* __restrict__ qbf, float* __restrict__ qf) {
    int blk = blockIdx.x;
    if (blk < CONVB) {
        size_t i = (size_t)blk * 256 + threadIdx.x;
        const float4* sp = (const float4*)emb + i * 2;
        float4 a = sp[0], b = sp[1];
        u16x8 o;
        o[0] = f2bf(a.x); o[1] = f2bf(a.y); o[2] = f2bf(a.z); o[3] = f2bf(a.w);
        o[4] = f2bf(b.x); o[5] = f2bf(b.y); o[6] = f2bf(b.z); o[7] = f2bf(b.w);
        *((u16x8*)ebf + i) = o;
    } else {
        int t = threadIdx.x;
        int b = (blk - CONVB) * 2 + (t >> 7);        // 2 batches per block
        int d = t & 127;
        int n = len[b];
        float s = 0.f;
        for (int l = 0; l < n; l++)
            s += emb[(size_t)seq[b * HLEN + l] * EDIM + d];
        float q = s / (float)(n > 0 ? n : 1);
        qbf[b * EDIM + d] = f2bf(q);
        qf [b * EDIM + d] = q;
    }
}

// ---- exact top-32 of a batch's candidate buffer: ballot-bisection on keys --
// CAP2 = 256 -> 4 elements per lane (verbatim from the R4-passing kernel).
__device__ inline void compact_batch(float* cv, int* ci, int* cnt, float* thr,
                                     int b, int lane) {
    int n = min(cnt[b], CAP2);
    float val[4]; int idx[4]; unsigned key[4];
    #pragma unroll
    for (int e = 0; e < 4; e++) {
        int i = lane + e * 64;
        if (i < n) {
            float v = cv[b * CAP2 + i];
            unsigned u = __float_as_uint(v);
            key[e] = (u & 0x80000000u) ? ~u : (u | 0x80000000u);
            val[e] = v; idx[e] = ci[b * CAP2 + i];
        } else { key[e] = 0u; val[e] = 0.f; idx[e] = 0; }
    }
    unsigned cur = 0u;                 // max T with count(key >= T) >= 32
    #pragma unroll 1
    for (int bit = 31; bit >= 0; bit--) {
        unsigned mid = cur | (1u << bit);
        int c = 0;
        #pragma unroll
        for (int e = 0; e < 4; e++)
            c += __popcll(__ballot(key[e] >= mid));
        if (c >= NKEEP) cur = mid;
    }
    int base = 0;                      // ballot prefix-sum compaction, no atomics
    #pragma unroll
    for (int e = 0; e < 4; e++) {
        bool keep = key[e] >= cur;
        unsigned long long m = __ballot(keep);
        int p = base + (int)__popcll(m & ((1ull << lane) - 1ull));
        if (keep && p < NKEEP) { cv[b * CAP2 + p] = val[e]; ci[b * CAP2 + p] = idx[e]; }
        base += (int)__popcll(m);
    }
    if (lane == 0) {
        cnt[b] = NKEEP;
        thr[b] = (cur & 0x80000000u) ? __uint_as_float(cur ^ 0x80000000u)
                                     : __uint_as_float(~cur);
    }
}

// ---------------- K2: bf16-MFMA scoring + fused per-range top-32 ------------
// FROZEN at the R12-passing version (315us; asm pin removed -- R10/R12 proved
// it null: afr already resident in AGPRs on gfx950's unified file, VGPR_Count
// only shows arch VGPRs). Cycle model closes: MFMA 931cy + VALU 1455cy of the
// 5727cy/SIMD-iter; the rest is per-wave latency that 3 waves/SIMD (register-
// file-capped: ~468/512 regs in use) cannot cover. Deeper unroll or 32x32
// MFMA would add >=32 regs -> spill (R6 precedent). Structural plateau.
__global__ __launch_bounds__(768, 3) void score_topk(
        const unsigned short* __restrict__ qbf,
        const unsigned short* __restrict__ ebf,
        int* __restrict__ candOut) {
    __shared__ float cv[MT * CAP2];    // 64 KB
    __shared__ int   ci[MT * CAP2];    // 64 KB
    __shared__ int   cnt[MT];
    __shared__ float thr[MT];

    const int tid  = threadIdx.x;
    const int lane = tid & 63;
    const int w    = tid >> 6;                       // wave 0..11
    const int r    = blockIdx.x & (VSPLIT - 1);      // V-range
    const int mg   = blockIdx.x / VSPLIT;            // batch group
    const int b0   = mg * MT;
    const int n15  = lane & 15, quad = lane >> 4;

    const int cstart = (r * NCHUNK_TOT) / VSPLIT;
    const int nch    = ((r + 1) * NCHUNK_TOT) / VSPLIT - cstart;  // 1562/1563

    if (tid < MT) { cnt[tid] = 0; thr[tid] = -INFINITY; }
    __syncthreads();

    // resident A-fragments: 4 msubs x 4 K-steps (64 regs, AGPR-resident)
    bf16x8 afr[MS][4];
    #pragma unroll
    for (int ms = 0; ms < MS; ms++)
        #pragma unroll
        for (int t = 0; t < 4; t++)
            afr[ms][t] = *(const bf16x8*)(qbf + (b0 + ms * 16 + n15) * EDIM
                                          + t * 32 + quad * 8);
    float thrR[MS * 4];
    #pragma unroll
    for (int i = 0; i < MS * 4; i++) thrR[i] = -INFINITY;

    const unsigned short* bbase = ebf + ((size_t)cstart * 16 + n15) * EDIM + quad * 8;

    int nextEvt = 1;

    // one iteration: MFMA+insert on `cur`, prefetch chunk(iter+1) into `nxt`
    auto body = [&](int iter, bf16x8 (&cur)[4], bf16x8 (&nxt)[4]) {
        {   // prefetch next iteration's B fragments
            int nit   = (iter + 1 < NITER) ? (iter + 1) : iter;
            int pch   = nit * NWAVE + w;
            int pcc   = (pch < nch) ? pch : (nch - 1);
            const unsigned short* bp = bbase + (size_t)pcc * (16 * EDIM);
            #pragma unroll
            for (int t = 0; t < 4; t++) nxt[t] = *(const bf16x8*)(bp + t * 32);
        }
        f32x4 acc[MS];
        #pragma unroll
        for (int ms = 0; ms < MS; ms++) acc[ms] = (f32x4){0.f, 0.f, 0.f, 0.f};
        #pragma unroll
        for (int t = 0; t < 4; t++)
            #pragma unroll
            for (int ms = 0; ms < MS; ms++)
                acc[ms] = __builtin_amdgcn_mfma_f32_16x16x32_bf16(afr[ms][t], cur[t], acc[ms], 0, 0, 0);

        int chunk = iter * NWAVE + w;
        bool act  = chunk < nch;                     // wave-uniform
        // C/D: item n = lane&15 (col), batch row = quad*4 + reg  [m89/m91]
        if (act) {
            int item = (cstart + chunk) * 16 + n15;
            float s[MS * 4]; bool pass[MS * 4]; bool hit = false;
            #pragma unroll
            for (int k = 0; k < MS * 4; k++) {
                float v = acc[k >> 2][k & 3];
                s[k] = v;
                pass[k] = (v > thrR[k]);
                hit |= pass[k];
            }
            if (__any(hit)) {                        // wave-uniform slow path
                int pz[MS * 4];
                // pass 1: issue all slot-reserving atomics, no waits between
                #pragma unroll
                for (int k = 0; k < MS * 4; k++) {
                    if (pass[k]) {
                        int row = (k >> 2) * 16 + (quad << 2) + (k & 3);
                        pz[k] = atomicAdd(&cnt[row], 1);
                    }
                }
                // keep all atomics above all stores so their latencies overlap
                __builtin_amdgcn_sched_barrier(0);
                // pass 2: one coalesced counted-lgkm wait, then stores
                #pragma unroll
                for (int k = 0; k < MS * 4; k++) {
                    if (pass[k] && pz[k] < CAP2) {
                        int row = (k >> 2) * 16 + (quad << 2) + (k & 3);
                        cv[row * CAP2 + pz[k]] = s[k];
                        ci[row * CAP2 + pz[k]] = item;
                    }
                }
            }
        }
        // static compaction schedule: iters 1,2,4,...,128, and the final iter.
        // Uniform across waves -> barrier counts always match. Trigger cnt>96
        // with CAP2=256: R4-proven headroom.
        if (iter + 1 == nextEvt || iter + 1 == NITER) {
            if (iter + 1 == nextEvt) nextEvt <<= 1;
            bool fin = (iter + 1 == NITER);
            __syncthreads();
            #pragma unroll 1
            for (int b = w; b < MT; b += NWAVE) {    // rows striped over 12 waves
                if (fin || cnt[b] > 96) compact_batch(cv, ci, cnt, thr, b, lane);
            }
            __syncthreads();
            #pragma unroll
            for (int ms = 0; ms < MS; ms++)
                #pragma unroll
                for (int rr = 0; rr < 4; rr++)
                    thrR[ms * 4 + rr] = thr[ms * 16 + (quad << 2) + rr];
        }
    };

    bf16x8 bA[4], bB[4];
    {   // preload iter 0
        int cc0 = (w < nch) ? w : (nch - 1);
        const unsigned short* bp = bbase + (size_t)cc0 * (16 * EDIM);
        #pragma unroll
        for (int t = 0; t < 4; t++) bA[t] = *(const bf16x8*)(bp + t * 32);
    }
    for (int iter = 0; iter < NITER; iter += 2) {    // NITER even: no tail
        body(iter,     bA, bB);
        body(iter + 1, bB, bA);
    }

    // final compact guaranteed cnt==32 per batch; emit candidate indices
    for (int b = w; b < MT; b += NWAVE) {
        if (lane < NKEEP)
            candOut[(b0 + b) * NCAND + r * NKEEP + lane] = ci[b * CAP2 + lane];
    }
}

// ---------------- K3: fp64 rescore of 128 candidates, exact top-21 ----------
// 512 threads, 4 threads/candidate: halves the per-thread load chain of the
// LLC-resident gather (vs R12's 2 threads/cand).
__global__ __launch_bounds__(512) void rescore(
        const float* __restrict__ qf, const float* __restrict__ emb,
        const int* __restrict__ cand, float* __restrict__ out) {
    __shared__ double qd[EDIM];
    __shared__ double sv[NCAND];
    __shared__ int    si[NCAND];
    int b = blockIdx.x, t = threadIdx.x;
    if (t < EDIM) qd[t] = (double)qf[b * EDIM + t];  // precomputed in prep
    __syncthreads();

    int c = t >> 2, h = t & 3;                       // 4 threads per candidate
    int idx = cand[b * NCAND + c];
    const float4* ev = (const float4*)(emb + (size_t)idx * EDIM + h * 32);
    double part = 0.0;
    #pragma unroll
    for (int j = 0; j < 8; j++) {
        float4 e = ev[j];
        int d = h * 32 + j * 4;
        part += qd[d] * (double)e.x + qd[d + 1] * (double)e.y
              + qd[d + 2] * (double)e.z + qd[d + 3] * (double)e.w;
    }
    part += __shfl_xor(part, 1);                     // combine quarters
    part += __shfl_xor(part, 2);
    if (h == 0) { sv[c] = part; si[c] = idx; }
    __syncthreads();

    if (t < NCAND) {                                 // rank among 128 (ties: low idx)
        double v = sv[t]; int id = si[t];
        int rank = 0;
        for (int j = 0; j < NCAND; j++) {
            double vj = sv[j]; int ij = si[j];
            rank += (vj > v || (vj == v && ij < id)) ? 1 : 0;
        }
        if (rank < TOPK) {
            out[(size_t)b * TOPK + rank] = (float)v;
            out[(size_t)BATCH * TOPK + (size_t)b * TOPK + rank] = (float)id;
        }
    }
}

extern "C" void kernel_launch(void* const* d_in, const int* in_sizes, int n_in,
                              void* d_out, int out_size, void* d_ws, size_t ws_size,
                              hipStream_t stream) {
    const int*   seq = (const int*)d_in[0];
    const int*   len = (const int*)d_in[1];
    const float* emb = (const float*)d_in[2];
    float* out = (float*)d_out;

    // ws: q_bf [4096*128 u16] | emb_bf [100000*128 u16] | cand [4096*128 i32]
    //     | q_f32 [4096*128 f32]   (~30.6 MB total)
    unsigned short* qbf  = (unsigned short*)d_ws;
    unsigned short* ebf  = qbf + (size_t)BATCH * EDIM;
    int*            cand = (int*)(ebf + (size_t)V_ITEMS * EDIM);
    float*          qf   = (float*)(cand + (size_t)BATCH * NCAND);

    prep      <<<CONVB + BATCH / 2, 256, 0, stream>>>(emb, ebf, seq, len, qbf, qf);
    score_topk<<<(BATCH / MT) * VSPLIT, 768, 0, stream>>>(qbf, ebf, cand);
    rescore   <<<BATCH, 512, 0, stream>>>(qf, emb, cand, out);
}

// Round 14
// 451.507 us; speedup vs baseline: 1.0680x; 1.0680x over previous
//
#include <hip/hip_runtime.h>
#include <stdint.h>

#define V_ITEMS 100000
#define EDIM    128
#define BATCH   4096
#define HLEN    50
#define TOPK    21

#define MT      64                      // batches per block in K2
#define MS      4                       // 16-row MFMA sub-blocks (MT/16)
#define VSPLIT  4                       // item-range splits (R4-proven overhead level)
#define NWAVE   12                      // waves per block (768 thr) -> 3 waves/SIMD
#define NCHUNK_TOT (V_ITEMS / 16)       // 6250 16-item chunks total
#define NITER   132                     // ceil(1563/12)=131 -> 132 (even)
#define CAP2    256                     // per-batch candidate capacity (R4-proven)
#define NKEEP   32                      // superset kept per (batch, range)
#define NCAND   (NKEEP * VSPLIT)        // 128 candidates per batch into K3

typedef __attribute__((ext_vector_type(8))) short          bf16x8;
typedef __attribute__((ext_vector_type(4))) float          f32x4;
typedef __attribute__((ext_vector_type(8))) unsigned short u16x8;

__device__ inline unsigned short f2bf(float x) {           // RNE fp32->bf16
    unsigned u = __float_as_uint(x);
    return (unsigned short)((u + 0x7FFFu + ((u >> 16) & 1u)) >> 16);
}

// ---------------- K0: emb fp32 -> bf16 table in ws --------------------------
__global__ __launch_bounds__(256) void conv_bf16(
        const float* __restrict__ s, unsigned short* __restrict__ d) {
    size_t i = (size_t)blockIdx.x * 256 + threadIdx.x;     // 8 floats/thread
    const float4* sp = (const float4*)s + i * 2;
    float4 a = sp[0], b = sp[1];
    u16x8 o;
    o[0] = f2bf(a.x); o[1] = f2bf(a.y); o[2] = f2bf(a.z); o[3] = f2bf(a.w);
    o[4] = f2bf(b.x); o[5] = f2bf(b.y); o[6] = f2bf(b.z); o[7] = f2bf(b.w);
    *((u16x8*)d + i) = o;
}

// ---------------- K1: masked mean-pool queries -> bf16 + fp32 ---------------
__global__ __launch_bounds__(EDIM) void query_bf16(
        const int* __restrict__ seq, const int* __restrict__ len,
        const float* __restrict__ emb, unsigned short* __restrict__ qbf,
        float* __restrict__ qf) {
    int b = blockIdx.x, d = threadIdx.x;
    int n = len[b];
    float s = 0.f;
    for (int l = 0; l < n; l++)
        s += emb[(size_t)seq[b * HLEN + l] * EDIM + d];
    float q = s / (float)(n > 0 ? n : 1);
    qbf[b * EDIM + d] = f2bf(q);
    qf [b * EDIM + d] = q;
}

// ---- exact top-32 of a batch's candidate buffer: ballot-bisection on keys --
// Packed uint2 {value bits, item}: 4 ds_read_b64/lane (was 8 b32 reads).
__device__ inline void compact_batch(uint2* cb, int* cnt, float* thr,
                                     int b, int lane) {
    int n = min(cnt[b], CAP2);
    unsigned key[4]; unsigned vraw[4]; unsigned item[4];
    #pragma unroll
    for (int e = 0; e < 4; e++) {
        int i = lane + e * 64;
        if (i < n) {
            uint2 d = cb[b * CAP2 + i];
            unsigned u = d.x;
            key[e] = (u & 0x80000000u) ? ~u : (u | 0x80000000u);
            vraw[e] = u; item[e] = d.y;
        } else { key[e] = 0u; vraw[e] = 0u; item[e] = 0u; }
    }
    unsigned cur = 0u;                 // max T with count(key >= T) >= 32
    #pragma unroll 1
    for (int bit = 31; bit >= 0; bit--) {
        unsigned mid = cur | (1u << bit);
        int c = 0;
        #pragma unroll
        for (int e = 0; e < 4; e++)
            c += __popcll(__ballot(key[e] >= mid));
        if (c >= NKEEP) cur = mid;
    }
    int base = 0;                      // ballot prefix-sum compaction, no atomics
    #pragma unroll
    for (int e = 0; e < 4; e++) {
        bool keep = key[e] >= cur;
        unsigned long long m = __ballot(keep);
        int p = base + (int)__popcll(m & ((1ull << lane) - 1ull));
        if (keep && p < NKEEP) cb[b * CAP2 + p] = make_uint2(vraw[e], item[e]);
        base += (int)__popcll(m);
    }
    if (lane == 0) {
        cnt[b] = NKEEP;
        thr[b] = (cur & 0x80000000u) ? __uint_as_float(cur ^ 0x80000000u)
                                     : __uint_as_float(~cur);
    }
}

// ---------------- K2: bf16-MFMA scoring + fused per-range top-32 ------------
// grid = 64 batch-groups x 4 V-ranges = 256 blocks (1/CU, single tranche),
// 768 threads = 12 waves = 3 waves/SIMD (LDS 128.5KB caps at 1 block/CU).
//
// Status after R8-R12: wave count is register-file-capped at 3/SIMD (unified
// VGPR+AGPR ~156/wave > 128 budget at 4 waves -- R6's spill cliff); remat/
// prefetch/insert-restructure experiments all null; kernel is latency-bound
// at 2.12 score-checks/cy/CU. R14's one remaining mechanical lever: packed
// uint2 candidate buffer -- 1 ds_write_b64 per insert (was 2 b32 stores) and
// 4 ds_read_b64 per compact-lane (was 8 b32 reads), one address stream fewer.
// Same LDS footprint, same R4-proven insert dynamics (iter0 flood 192<=256,
// trigger>96). If this is ALSO null, the plateau is structural -> revert to
// byte-exact R12 and stop.
__global__ __launch_bounds__(768, 3) void score_topk(
        const unsigned short* __restrict__ qbf,
        const unsigned short* __restrict__ ebf,
        int* __restrict__ candOut) {
    __shared__ uint2 cb[MT * CAP2];    // 128 KB packed {value bits, item}
    __shared__ int   cnt[MT];
    __shared__ float thr[MT];

    const int tid  = threadIdx.x;
    const int lane = tid & 63;
    const int w    = tid >> 6;                       // wave 0..11
    const int r    = blockIdx.x & (VSPLIT - 1);      // V-range
    const int mg   = blockIdx.x / VSPLIT;            // batch group
    const int b0   = mg * MT;
    const int n15  = lane & 15, quad = lane >> 4;

    const int cstart = (r * NCHUNK_TOT) / VSPLIT;
    const int nch    = ((r + 1) * NCHUNK_TOT) / VSPLIT - cstart;  // 1562/1563

    if (tid < MT) { cnt[tid] = 0; thr[tid] = -INFINITY; }
    __syncthreads();

    // resident A-fragments: 4 msubs x 4 K-steps (64 regs, AGPR-resident)
    bf16x8 afr[MS][4];
    #pragma unroll
    for (int ms = 0; ms < MS; ms++)
        #pragma unroll
        for (int t = 0; t < 4; t++)
            afr[ms][t] = *(const bf16x8*)(qbf + (b0 + ms * 16 + n15) * EDIM
                                          + t * 32 + quad * 8);
    float thrR[MS * 4];
    #pragma unroll
    for (int i = 0; i < MS * 4; i++) thrR[i] = -INFINITY;

    const unsigned short* bbase = ebf + ((size_t)cstart * 16 + n15) * EDIM + quad * 8;

    int nextEvt = 1;

    // one iteration: MFMA+insert on `cur`, prefetch chunk(iter+1) into `nxt`
    auto body = [&](int iter, bf16x8 (&cur)[4], bf16x8 (&nxt)[4]) {
        {   // prefetch next iteration's B fragments
            int nit   = (iter + 1 < NITER) ? (iter + 1) : iter;
            int pch   = nit * NWAVE + w;
            int pcc   = (pch < nch) ? pch : (nch - 1);
            const unsigned short* bp = bbase + (size_t)pcc * (16 * EDIM);
            #pragma unroll
            for (int t = 0; t < 4; t++) nxt[t] = *(const bf16x8*)(bp + t * 32);
        }
        f32x4 acc[MS];
        #pragma unroll
        for (int ms = 0; ms < MS; ms++) acc[ms] = (f32x4){0.f, 0.f, 0.f, 0.f};
        #pragma unroll
        for (int t = 0; t < 4; t++)
            #pragma unroll
            for (int ms = 0; ms < MS; ms++)
                acc[ms] = __builtin_amdgcn_mfma_f32_16x16x32_bf16(afr[ms][t], cur[t], acc[ms], 0, 0, 0);

        int chunk = iter * NWAVE + w;
        bool act  = chunk < nch;                     // wave-uniform
        // C/D: item n = lane&15 (col), batch row = quad*4 + reg  [m89/m91]
        if (act) {
            unsigned item = (unsigned)((cstart + chunk) * 16 + n15);
            float s[MS * 4]; bool pass[MS * 4]; bool hit = false;
            #pragma unroll
            for (int k = 0; k < MS * 4; k++) {
                float v = acc[k >> 2][k & 3];
                s[k] = v;
                pass[k] = (v > thrR[k]);
                hit |= pass[k];
            }
            if (__any(hit)) {                        // wave-uniform slow path
                int pz[MS * 4];
                // pass 1: issue all slot-reserving atomics, no waits between
                #pragma unroll
                for (int k = 0; k < MS * 4; k++) {
                    if (pass[k]) {
                        int row = (k >> 2) * 16 + (quad << 2) + (k & 3);
                        pz[k] = atomicAdd(&cnt[row], 1);
                    }
                }
                // keep all atomics above all stores so their latencies overlap
                __builtin_amdgcn_sched_barrier(0);
                // pass 2: single packed ds_write_b64 per accepted candidate
                #pragma unroll
                for (int k = 0; k < MS * 4; k++) {
                    if (pass[k] && pz[k] < CAP2) {
                        int row = (k >> 2) * 16 + (quad << 2) + (k & 3);
                        cb[row * CAP2 + pz[k]] =
                            make_uint2(__float_as_uint(s[k]), item);
                    }
                }
            }
        }
        // static compaction schedule: iters 1,2,4,...,128, and the final iter.
        // Uniform across waves -> barrier counts always match. Trigger cnt>96
        // with CAP2=256: R4-proven headroom.
        if (iter + 1 == nextEvt || iter + 1 == NITER) {
            if (iter + 1 == nextEvt) nextEvt <<= 1;
            bool fin = (iter + 1 == NITER);
            __syncthreads();
            #pragma unroll 1
            for (int b = w; b < MT; b += NWAVE) {    // rows striped over 12 waves
                if (fin || cnt[b] > 96) compact_batch(cb, cnt, thr, b, lane);
            }
            __syncthreads();
            #pragma unroll
            for (int ms = 0; ms < MS; ms++)
                #pragma unroll
                for (int rr = 0; rr < 4; rr++)
                    thrR[ms * 4 + rr] = thr[ms * 16 + (quad << 2) + rr];
        }
    };

    bf16x8 bA[4], bB[4];
    {   // preload iter 0
        int cc0 = (w < nch) ? w : (nch - 1);
        const unsigned short* bp = bbase + (size_t)cc0 * (16 * EDIM);
        #pragma unroll
        for (int t = 0; t < 4; t++) bA[t] = *(const bf16x8*)(bp + t * 32);
    }
    for (int iter = 0; iter < NITER; iter += 2) {    // NITER even: no tail
        body(iter,     bA, bB);
        body(iter + 1, bB, bA);
    }

    // final compact guaranteed cnt==32 per batch; emit candidate indices
    for (int b = w; b < MT; b += NWAVE) {
        if (lane < NKEEP)
            candOut[(b0 + b) * NCAND + r * NKEEP + lane] =
                (int)cb[b * CAP2 + lane].y;
    }
}

// ---------------- K3: fp64 rescore of 128 candidates, exact top-21 ----------
__global__ __launch_bounds__(256) void rescore(
        const float* __restrict__ qf, const float* __restrict__ emb,
        const int* __restrict__ cand, float* __restrict__ out) {
    __shared__ double qd[EDIM];
    __shared__ double sv[NCAND];
    __shared__ int    si[NCAND];
    int b = blockIdx.x, t = threadIdx.x;
    if (t < EDIM) qd[t] = (double)qf[b * EDIM + t];  // precomputed in K1
    __syncthreads();

    int c = t >> 1, h = t & 1;                       // 2 threads per candidate
    int idx = cand[b * NCAND + c];
    const float4* ev = (const float4*)(emb + (size_t)idx * EDIM + h * 64);
    double part = 0.0;
    #pragma unroll 4
    for (int j = 0; j < 16; j++) {
        float4 e = ev[j];
        int d = h * 64 + j * 4;
        part += qd[d] * (double)e.x + qd[d + 1] * (double)e.y
              + qd[d + 2] * (double)e.z + qd[d + 3] * (double)e.w;
    }
    part += __shfl_xor(part, 1);                     // combine halves
    if (h == 0) { sv[c] = part; si[c] = idx; }
    __syncthreads();

    if (t < NCAND) {                                 // rank among 128 (ties: low idx)
        double v = sv[t]; int id = si[t];
        int rank = 0;
        for (int j = 0; j < NCAND; j++) {
            double vj = sv[j]; int ij = si[j];
            rank += (vj > v || (vj == v && ij < id)) ? 1 : 0;
        }
        if (rank < TOPK) {
            out[(size_t)b * TOPK + rank] = (float)v;
            out[(size_t)BATCH * TOPK + (size_t)b * TOPK + rank] = (float)id;
        }
    }
}

extern "C" void kernel_launch(void* const* d_in, const int* in_sizes, int n_in,
                              void* d_out, int out_size, void* d_ws, size_t ws_size,
                              hipStream_t stream) {
    const int*   seq = (const int*)d_in[0];
    const int*   len = (const int*)d_in[1];
    const float* emb = (const float*)d_in[2];
    float* out = (float*)d_out;

    // ws: q_bf [4096*128 u16] | emb_bf [100000*128 u16] | cand [4096*128 i32]
    //     | q_f32 [4096*128 f32]   (~30.6 MB total)
    unsigned short* qbf  = (unsigned short*)d_ws;
    unsigned short* ebf  = qbf + (size_t)BATCH * EDIM;
    int*            cand = (int*)(ebf + (size_t)V_ITEMS * EDIM);
    float*          qf   = (float*)(cand + (size_t)BATCH * NCAND);

    conv_bf16 <<<(V_ITEMS * EDIM) / (256 * 8), 256, 0, stream>>>(emb, ebf);
    query_bf16<<<BATCH, EDIM, 0, stream>>>(seq, len, emb, qbf, qf);
    score_topk<<<(BATCH / MT) * VSPLIT, 768, 0, stream>>>(qbf, ebf, cand);
    rescore   <<<BATCH, 256, 0, stream>>>(qf, emb, cand, out);
}